// Round 1
// baseline (2853.813 us; speedup 1.0000x reference)
//
#include <hip/hip_runtime.h>
#include <hip/hip_bf16.h>
#include <cstdint>
#include <cstddef>

// LlamaCompressedMLP on MI355X (gfx950).
// x[4096,4096] f32 ; w_gate_up[22016,4096] f32 ; w_down[4096,11008] f32
// out[4096,4096] f32.  bf16 MFMA (16x16x32), fp32 accumulate.

typedef __attribute__((ext_vector_type(8))) short short8;
typedef __attribute__((ext_vector_type(4))) float f32x4;
typedef __attribute__((ext_vector_type(4))) unsigned short ushort4v;

#define HID   4096
#define INTER 11008

static __device__ __forceinline__ unsigned short f2bf(float f) {
  union { float f; unsigned int u; } v; v.f = f;
  unsigned int u = v.u;
  // round-to-nearest-even bf16
  unsigned int r = (u + 0x7FFFu + ((u >> 16) & 1u)) >> 16;
  return (unsigned short)r;
}

// ---------------------------------------------------------------------------
// GEMM1 (fused): C = x . w_gate_up^T for both halves, SwiGLU epilogue -> h bf16
// Block tile: 128 rows (M) x 64 cols (of I), dual-B (gate rows n, up rows n+I).
// 256 threads = 4 waves, each wave 64x32 per acc set. BK=32.
// ---------------------------------------------------------------------------
__global__ __launch_bounds__(256, 2)
void gemm1_kernel(const float* __restrict__ A,          // [chunk_rows, HID]
                  const float* __restrict__ W,          // [2*INTER, HID]
                  unsigned short* __restrict__ Hout)    // [chunk_rows, INTER] bf16
{
  __shared__ unsigned short lA[4][128][8];   // [kblk][row^ (2*kblk)][8]
  __shared__ unsigned short lB[4][128][8];   // rows 0-63 gate, 64-127 up

  const int t    = threadIdx.x;
  const int lane = t & 63;
  const int wv   = t >> 6;
  const int wr   = wv >> 1;        // 0..1 : 64-row block
  const int wc   = wv & 1;         // 0..1 : 32-col block
  const int fr   = lane & 15;
  const int kb   = lane >> 4;

  const int m0 = blockIdx.x * 128;
  const int n0 = blockIdx.y * 64;

  // staging coords (fp32 source): thread t covers row (t>>3)+32i, k-chunk (t&7)*4
  const int srow  = t >> 3;
  const int scol  = (t & 7) * 4;
  const int skb   = (t & 7) >> 1;
  const int shalf = t & 1;

  f32x4 accg[4][2], accu[4][2];
  const f32x4 z = {0.f, 0.f, 0.f, 0.f};
#pragma unroll
  for (int m = 0; m < 4; ++m)
#pragma unroll
    for (int n = 0; n < 2; ++n) { accg[m][n] = z; accu[m][n] = z; }

  for (int k0 = 0; k0 < HID; k0 += 32) {
    // ---- stage A (fp32 -> bf16) : 128x32
#pragma unroll
    for (int i = 0; i < 4; ++i) {
      const int row = srow + 32 * i;
      const float4 v = *reinterpret_cast<const float4*>(
          &A[(size_t)(m0 + row) * HID + k0 + scol]);
      ushort4v p;
      p.x = f2bf(v.x); p.y = f2bf(v.y); p.z = f2bf(v.z); p.w = f2bf(v.w);
      *reinterpret_cast<ushort4v*>(&lA[skb][row ^ (skb * 2)][shalf * 4]) = p;
    }
    // ---- stage B dual (gate rows then up rows)
#pragma unroll
    for (int i = 0; i < 4; ++i) {
      const int row = srow + 32 * i;   // 0..127 ; <64 gate, >=64 up
      const size_t grow = (row < 64) ? (size_t)(n0 + row)
                                     : (size_t)(INTER + n0 + row - 64);
      const float4 v = *reinterpret_cast<const float4*>(
          &W[grow * HID + k0 + scol]);
      ushort4v p;
      p.x = f2bf(v.x); p.y = f2bf(v.y); p.z = f2bf(v.z); p.w = f2bf(v.w);
      *reinterpret_cast<ushort4v*>(&lB[skb][row ^ (skb * 2)][shalf * 4]) = p;
    }
    __syncthreads();

    short8 af[4], bg[2], bu[2];
#pragma unroll
    for (int m = 0; m < 4; ++m) {
      const int r = wr * 64 + m * 16 + fr;
      af[m] = *reinterpret_cast<const short8*>(&lA[kb][r ^ (kb * 2)][0]);
    }
#pragma unroll
    for (int n = 0; n < 2; ++n) {
      const int rg = wc * 32 + n * 16 + fr;
      bg[n] = *reinterpret_cast<const short8*>(&lB[kb][rg ^ (kb * 2)][0]);
      bu[n] = *reinterpret_cast<const short8*>(&lB[kb][(rg + 64) ^ (kb * 2)][0]);
    }
#pragma unroll
    for (int m = 0; m < 4; ++m)
#pragma unroll
      for (int n = 0; n < 2; ++n) {
        accg[m][n] = __builtin_amdgcn_mfma_f32_16x16x32_bf16(af[m], bg[n], accg[m][n], 0, 0, 0);
        accu[m][n] = __builtin_amdgcn_mfma_f32_16x16x32_bf16(af[m], bu[n], accu[m][n], 0, 0, 0);
      }
    __syncthreads();
  }

  // ---- SwiGLU epilogue -> bf16 h
#pragma unroll
  for (int m = 0; m < 4; ++m)
#pragma unroll
    for (int n = 0; n < 2; ++n)
#pragma unroll
      for (int r = 0; r < 4; ++r) {
        const int row = m0 + wr * 64 + m * 16 + (lane >> 4) * 4 + r;
        const int col = n0 + wc * 32 + n * 16 + fr;
        const float g = accg[m][n][r];
        const float u = accu[m][n][r];
        const float s = g / (1.0f + __expf(-g));   // silu(g)
        Hout[(size_t)row * INTER + col] = f2bf(s * u);
      }
}

// ---------------------------------------------------------------------------
// GEMM2: out = h . w_down^T.  A bf16 [chunk,INTER], B fp32 [HID, INTER].
// Block tile 128x128, 4 waves each 64x64. BK=32.
// ---------------------------------------------------------------------------
__global__ __launch_bounds__(256, 2)
void gemm2_kernel(const unsigned short* __restrict__ Hin, // [chunk_rows, INTER] bf16
                  const float* __restrict__ W,            // [HID, INTER]
                  float* __restrict__ Out)                // [chunk_rows, HID]
{
  __shared__ unsigned short lA[4][128][8];
  __shared__ unsigned short lB[4][128][8];

  const int t    = threadIdx.x;
  const int lane = t & 63;
  const int wv   = t >> 6;
  const int wr   = wv >> 1;
  const int wc   = wv & 1;
  const int fr   = lane & 15;
  const int kb   = lane >> 4;

  const int m0 = blockIdx.x * 128;
  const int n0 = blockIdx.y * 128;

  const int srow  = t >> 3;
  const int scol  = (t & 7) * 4;
  const int skb   = (t & 7) >> 1;
  const int shalf = t & 1;

  f32x4 acc[4][4];
  const f32x4 z = {0.f, 0.f, 0.f, 0.f};
#pragma unroll
  for (int m = 0; m < 4; ++m)
#pragma unroll
    for (int n = 0; n < 4; ++n) acc[m][n] = z;

  for (int k0 = 0; k0 < INTER; k0 += 32) {
    // ---- stage A (already bf16): 128x32, 16B chunks
#pragma unroll
    for (int i = 0; i < 2; ++i) {
      const int row  = (t >> 2) + 64 * i;
      const int kblk = t & 3;
      const uint4 v = *reinterpret_cast<const uint4*>(
          &Hin[(size_t)(m0 + row) * INTER + k0 + kblk * 8]);
      *reinterpret_cast<uint4*>(&lA[kblk][row ^ (kblk * 2)][0]) = v;
    }
    // ---- stage B (fp32 -> bf16)
#pragma unroll
    for (int i = 0; i < 4; ++i) {
      const int row = srow + 32 * i;
      const float4 v = *reinterpret_cast<const float4*>(
          &W[(size_t)(n0 + row) * INTER + k0 + scol]);
      ushort4v p;
      p.x = f2bf(v.x); p.y = f2bf(v.y); p.z = f2bf(v.z); p.w = f2bf(v.w);
      *reinterpret_cast<ushort4v*>(&lB[skb][row ^ (skb * 2)][shalf * 4]) = p;
    }
    __syncthreads();

    short8 af[4], bf_[4];
#pragma unroll
    for (int m = 0; m < 4; ++m) {
      const int r = wr * 64 + m * 16 + fr;
      af[m] = *reinterpret_cast<const short8*>(&lA[kb][r ^ (kb * 2)][0]);
    }
#pragma unroll
    for (int n = 0; n < 4; ++n) {
      const int r = wc * 64 + n * 16 + fr;
      bf_[n] = *reinterpret_cast<const short8*>(&lB[kb][r ^ (kb * 2)][0]);
    }
#pragma unroll
    for (int m = 0; m < 4; ++m)
#pragma unroll
      for (int n = 0; n < 4; ++n)
        acc[m][n] = __builtin_amdgcn_mfma_f32_16x16x32_bf16(af[m], bf_[n], acc[m][n], 0, 0, 0);
    __syncthreads();
  }

#pragma unroll
  for (int m = 0; m < 4; ++m)
#pragma unroll
    for (int n = 0; n < 4; ++n)
#pragma unroll
      for (int r = 0; r < 4; ++r) {
        const int row = m0 + wr * 64 + m * 16 + (lane >> 4) * 4 + r;
        const int col = n0 + wc * 64 + n * 16 + fr;
        Out[(size_t)row * HID + col] = acc[m][n][r];
      }
}

// ---------------------------------------------------------------------------
extern "C" void kernel_launch(void* const* d_in, const int* in_sizes, int n_in,
                              void* d_out, int out_size, void* d_ws, size_t ws_size,
                              hipStream_t stream) {
  const float* x   = (const float*)d_in[0];   // [2,2048,4096] = [4096,4096]
  const float* wgu = (const float*)d_in[1];   // [22016,4096]
  const float* wdn = (const float*)d_in[2];   // [4096,11008]
  float* out = (float*)d_out;
  unsigned short* hbuf = (unsigned short*)d_ws;

  const int M = 4096;
  const size_t bytes_per_row = (size_t)INTER * sizeof(unsigned short);
  // largest multiple-of-128 row chunk of h that fits in workspace
  size_t rows_fit = ws_size / bytes_per_row;
  int chunk = (int)(rows_fit & ~(size_t)127);
  if (chunk <= 0) chunk = 128;          // minimum viable (needs ~2.75 MB ws)
  if (chunk > M) chunk = M;

  for (int m0 = 0; m0 < M; m0 += chunk) {
    const int mrows = (M - m0 < chunk) ? (M - m0) : chunk;
    dim3 g1(mrows / 128, INTER / 64);   // 64-col dual tiles over I
    gemm1_kernel<<<g1, dim3(256), 0, stream>>>(x + (size_t)m0 * HID, wgu, hbuf);
    dim3 g2(mrows / 128, HID / 128);
    gemm2_kernel<<<g2, dim3(256), 0, stream>>>(hbuf, wdn, out + (size_t)m0 * HID);
  }
}

// Round 2
// 2209.700 us; speedup vs baseline: 1.2915x; 1.2915x over previous
//
#include <hip/hip_runtime.h>
#include <hip/hip_bf16.h>
#include <cstdint>
#include <cstddef>

// LlamaCompressedMLP on MI355X (gfx950).
// x[4096,4096] f32 ; w_gate_up[22016,4096] f32 ; w_down[4096,11008] f32
// out[4096,4096] f32.
// R1: pre-convert operands to bf16 in d_ws, then m97-style GEMMs:
//     global_load_lds(16B) staging, BK=32, 128-tile, chunk-XOR LDS swizzle
//     (inverse-swizzled global source, linear LDS dest), XCD block swizzle.

typedef __attribute__((ext_vector_type(8))) short short8;
typedef __attribute__((ext_vector_type(4))) float f32x4;
typedef __attribute__((ext_vector_type(4))) unsigned short ushort4v;

#define HID   4096
#define INTER 11008
#define MTOT  4096

static __device__ __forceinline__ unsigned short f2bf(float f) {
  union { float f; unsigned int u; } v; v.f = f;
  unsigned int u = v.u;
  unsigned int r = (u + 0x7FFFu + ((u >> 16) & 1u)) >> 16;  // RNE
  return (unsigned short)r;
}

static __device__ __forceinline__ void gload_lds16(const unsigned short* g,
                                                   unsigned short* l) {
  __builtin_amdgcn_global_load_lds(
      (const __attribute__((address_space(1))) void*)g,
      (__attribute__((address_space(3))) void*)l, 16, 0, 0);
}

// ---------------------------------------------------------------------------
// fp32 -> bf16 conversion, 32B-read / 16B-write per thread, grid-stride.
// ---------------------------------------------------------------------------
__global__ __launch_bounds__(256)
void cvt_kernel(const float* __restrict__ src, unsigned short* __restrict__ dst,
                long n8) {
  long i = (long)blockIdx.x * blockDim.x + threadIdx.x;
  const long stride = (long)gridDim.x * blockDim.x;
  for (; i < n8; i += stride) {
    const float4* s = reinterpret_cast<const float4*>(src) + i * 2;
    const float4 v0 = s[0], v1 = s[1];
    uint4 q;
    q.x = (unsigned)f2bf(v0.x) | ((unsigned)f2bf(v0.y) << 16);
    q.y = (unsigned)f2bf(v0.z) | ((unsigned)f2bf(v0.w) << 16);
    q.z = (unsigned)f2bf(v1.x) | ((unsigned)f2bf(v1.y) << 16);
    q.w = (unsigned)f2bf(v1.z) | ((unsigned)f2bf(v1.w) << 16);
    reinterpret_cast<uint4*>(dst)[i] = q;
  }
}

// ---------------------------------------------------------------------------
// GEMM1 fast: h = SwiGLU(x . wgu^T). A,W bf16. Tile 128M x 64N dual-B. BK=32.
// ---------------------------------------------------------------------------
__global__ __launch_bounds__(256, 2)
void gemm1_fast(const unsigned short* __restrict__ A,   // [CM, HID]
                const unsigned short* __restrict__ W,   // [2*INTER, HID]
                unsigned short* __restrict__ Hout,      // [CM, INTER]
                int mt) {
  __shared__ __align__(16) unsigned short lA[128 * 32];
  __shared__ __align__(16) unsigned short lB[128 * 32];

  const int t    = threadIdx.x;
  const int lane = t & 63;
  const int wv   = t >> 6;
  const int fr   = lane & 15;
  const int kb   = lane >> 4;
  const int wr   = wv >> 1, wc = wv & 1;

  // bijective XCD swizzle (m204)
  const int nwg = gridDim.x;
  const int q = nwg >> 3, r = nwg & 7, xc = blockIdx.x & 7, o = blockIdx.x >> 3;
  const int swz = (xc < r ? xc * (q + 1) : r * (q + 1) + (xc - r) * q) + o;
  const int m0 = (swz % mt) * 128;
  const int n0 = (swz / mt) * 64;

  // staging coords: wave issue covers 16 rows x 32 cols (1024 B linear LDS)
  const int rl0 = (wv * 2 + 0) * 16 + (lane >> 2);
  const int rl1 = (wv * 2 + 1) * 16 + (lane >> 2);
  const int sc  = lane & 3;
  const int g0  = sc ^ ((rl0 >> 1) & 3);
  const int g1  = sc ^ ((rl1 >> 1) & 3);

  const unsigned short* aS0 = A + (size_t)(m0 + rl0) * HID + g0 * 8;
  const unsigned short* aS1 = A + (size_t)(m0 + rl1) * HID + g1 * 8;
  const size_t gr0 = (rl0 < 64) ? (size_t)(n0 + rl0) : (size_t)(INTER + n0 + rl0 - 64);
  const size_t gr1 = (rl1 < 64) ? (size_t)(n0 + rl1) : (size_t)(INTER + n0 + rl1 - 64);
  const unsigned short* bS0 = W + gr0 * HID + g0 * 8;
  const unsigned short* bS1 = W + gr1 * HID + g1 * 8;
  unsigned short* lA0 = &lA[(wv * 2 + 0) * 512];
  unsigned short* lA1 = &lA[(wv * 2 + 1) * 512];
  unsigned short* lB0 = &lB[(wv * 2 + 0) * 512];
  unsigned short* lB1 = &lB[(wv * 2 + 1) * 512];

  f32x4 accg[4][2], accu[4][2];
  const f32x4 z = {0.f, 0.f, 0.f, 0.f};
#pragma unroll
  for (int m = 0; m < 4; ++m)
#pragma unroll
    for (int n = 0; n < 2; ++n) { accg[m][n] = z; accu[m][n] = z; }

  for (int k0 = 0; k0 < HID; k0 += 32) {
    gload_lds16(aS0 + k0, lA0);
    gload_lds16(aS1 + k0, lA1);
    gload_lds16(bS0 + k0, lB0);
    gload_lds16(bS1 + k0, lB1);
    __syncthreads();

    short8 a[4], bg[2], bu[2];
#pragma unroll
    for (int m = 0; m < 4; ++m) {
      const int rr = wr * 64 + m * 16 + fr;
      a[m] = *reinterpret_cast<const short8*>(&lA[rr * 32 + (kb ^ ((rr >> 1) & 3)) * 8]);
    }
#pragma unroll
    for (int n = 0; n < 2; ++n) {
      const int rg = wc * 32 + n * 16 + fr;
      bg[n] = *reinterpret_cast<const short8*>(&lB[rg * 32 + (kb ^ ((rg >> 1) & 3)) * 8]);
      const int ru = rg + 64;
      bu[n] = *reinterpret_cast<const short8*>(&lB[ru * 32 + (kb ^ ((ru >> 1) & 3)) * 8]);
    }
#pragma unroll
    for (int m = 0; m < 4; ++m)
#pragma unroll
      for (int n = 0; n < 2; ++n) {
        accg[m][n] = __builtin_amdgcn_mfma_f32_16x16x32_bf16(a[m], bg[n], accg[m][n], 0, 0, 0);
        accu[m][n] = __builtin_amdgcn_mfma_f32_16x16x32_bf16(a[m], bu[n], accu[m][n], 0, 0, 0);
      }
    __syncthreads();
  }

#pragma unroll
  for (int m = 0; m < 4; ++m)
#pragma unroll
    for (int n = 0; n < 2; ++n)
#pragma unroll
      for (int rr = 0; rr < 4; ++rr) {
        const int row = m0 + wr * 64 + m * 16 + kb * 4 + rr;
        const int col = n0 + wc * 32 + n * 16 + fr;
        const float g = accg[m][n][rr];
        const float u = accu[m][n][rr];
        const float s = g / (1.0f + __expf(-g));
        Hout[(size_t)row * INTER + col] = f2bf(s * u);
      }
}

// ---------------------------------------------------------------------------
// GEMM2 fast: out = h . wdn^T. A,W bf16, out fp32. Tile 128x128. BK=32.
// ---------------------------------------------------------------------------
__global__ __launch_bounds__(256, 2)
void gemm2_fast(const unsigned short* __restrict__ A,   // [CM, INTER]
                const unsigned short* __restrict__ W,   // [HID, INTER]
                float* __restrict__ Out,                // [CM, HID]
                int mt) {
  __shared__ __align__(16) unsigned short lA[128 * 32];
  __shared__ __align__(16) unsigned short lB[128 * 32];

  const int t    = threadIdx.x;
  const int lane = t & 63;
  const int wv   = t >> 6;
  const int fr   = lane & 15;
  const int kb   = lane >> 4;
  const int wr   = wv >> 1, wc = wv & 1;

  const int nwg = gridDim.x;
  const int q = nwg >> 3, r = nwg & 7, xc = blockIdx.x & 7, o = blockIdx.x >> 3;
  const int swz = (xc < r ? xc * (q + 1) : r * (q + 1) + (xc - r) * q) + o;
  const int m0 = (swz % mt) * 128;
  const int n0 = (swz / mt) * 128;

  const int rl0 = (wv * 2 + 0) * 16 + (lane >> 2);
  const int rl1 = (wv * 2 + 1) * 16 + (lane >> 2);
  const int sc  = lane & 3;
  const int g0  = sc ^ ((rl0 >> 1) & 3);
  const int g1  = sc ^ ((rl1 >> 1) & 3);

  const unsigned short* aS0 = A + (size_t)(m0 + rl0) * INTER + g0 * 8;
  const unsigned short* aS1 = A + (size_t)(m0 + rl1) * INTER + g1 * 8;
  const unsigned short* bS0 = W + (size_t)(n0 + rl0) * INTER + g0 * 8;
  const unsigned short* bS1 = W + (size_t)(n0 + rl1) * INTER + g1 * 8;
  unsigned short* lA0 = &lA[(wv * 2 + 0) * 512];
  unsigned short* lA1 = &lA[(wv * 2 + 1) * 512];
  unsigned short* lB0 = &lB[(wv * 2 + 0) * 512];
  unsigned short* lB1 = &lB[(wv * 2 + 1) * 512];

  f32x4 acc[4][4];
  const f32x4 z = {0.f, 0.f, 0.f, 0.f};
#pragma unroll
  for (int m = 0; m < 4; ++m)
#pragma unroll
    for (int n = 0; n < 4; ++n) acc[m][n] = z;

  for (int k0 = 0; k0 < INTER; k0 += 32) {
    gload_lds16(aS0 + k0, lA0);
    gload_lds16(aS1 + k0, lA1);
    gload_lds16(bS0 + k0, lB0);
    gload_lds16(bS1 + k0, lB1);
    __syncthreads();

    short8 a[4], b[4];
#pragma unroll
    for (int m = 0; m < 4; ++m) {
      const int rr = wr * 64 + m * 16 + fr;
      a[m] = *reinterpret_cast<const short8*>(&lA[rr * 32 + (kb ^ ((rr >> 1) & 3)) * 8]);
    }
#pragma unroll
    for (int n = 0; n < 4; ++n) {
      const int rb = wc * 64 + n * 16 + fr;
      b[n] = *reinterpret_cast<const short8*>(&lB[rb * 32 + (kb ^ ((rb >> 1) & 3)) * 8]);
    }
#pragma unroll
    for (int m = 0; m < 4; ++m)
#pragma unroll
      for (int n = 0; n < 4; ++n)
        acc[m][n] = __builtin_amdgcn_mfma_f32_16x16x32_bf16(a[m], b[n], acc[m][n], 0, 0, 0);
    __syncthreads();
  }

#pragma unroll
  for (int m = 0; m < 4; ++m)
#pragma unroll
    for (int n = 0; n < 4; ++n)
#pragma unroll
      for (int rr = 0; rr < 4; ++rr) {
        const int row = m0 + wr * 64 + m * 16 + kb * 4 + rr;
        const int col = n0 + wc * 64 + n * 16 + fr;
        Out[(size_t)row * HID + col] = acc[m][n][rr];
      }
}

// ---------------------------------------------------------------------------
// Fallback (baseline, reg-cvt fp32 staging) — used only if ws_size too small.
// ---------------------------------------------------------------------------
__global__ __launch_bounds__(256, 2)
void gemm1_slow(const float* __restrict__ A, const float* __restrict__ W,
                unsigned short* __restrict__ Hout) {
  __shared__ unsigned short lA[4][128][8];
  __shared__ unsigned short lB[4][128][8];
  const int t = threadIdx.x, lane = t & 63, wv = t >> 6;
  const int wr = wv >> 1, wc = wv & 1, fr = lane & 15, kb = lane >> 4;
  const int m0 = blockIdx.x * 128, n0 = blockIdx.y * 64;
  const int srow = t >> 3, scol = (t & 7) * 4, skb = (t & 7) >> 1, shalf = t & 1;
  f32x4 accg[4][2], accu[4][2];
  const f32x4 z = {0.f, 0.f, 0.f, 0.f};
#pragma unroll
  for (int m = 0; m < 4; ++m)
#pragma unroll
    for (int n = 0; n < 2; ++n) { accg[m][n] = z; accu[m][n] = z; }
  for (int k0 = 0; k0 < HID; k0 += 32) {
#pragma unroll
    for (int i = 0; i < 4; ++i) {
      const int row = srow + 32 * i;
      const float4 v = *reinterpret_cast<const float4*>(&A[(size_t)(m0 + row) * HID + k0 + scol]);
      ushort4v p; p.x = f2bf(v.x); p.y = f2bf(v.y); p.z = f2bf(v.z); p.w = f2bf(v.w);
      *reinterpret_cast<ushort4v*>(&lA[skb][row ^ (skb * 2)][shalf * 4]) = p;
    }
#pragma unroll
    for (int i = 0; i < 4; ++i) {
      const int row = srow + 32 * i;
      const size_t grow = (row < 64) ? (size_t)(n0 + row) : (size_t)(INTER + n0 + row - 64);
      const float4 v = *reinterpret_cast<const float4*>(&W[grow * HID + k0 + scol]);
      ushort4v p; p.x = f2bf(v.x); p.y = f2bf(v.y); p.z = f2bf(v.z); p.w = f2bf(v.w);
      *reinterpret_cast<ushort4v*>(&lB[skb][row ^ (skb * 2)][shalf * 4]) = p;
    }
    __syncthreads();
    short8 a[4], bg[2], bu[2];
#pragma unroll
    for (int m = 0; m < 4; ++m) {
      const int rr = wr * 64 + m * 16 + fr;
      a[m] = *reinterpret_cast<const short8*>(&lA[kb][rr ^ (kb * 2)][0]);
    }
#pragma unroll
    for (int n = 0; n < 2; ++n) {
      const int rg = wc * 32 + n * 16 + fr;
      bg[n] = *reinterpret_cast<const short8*>(&lB[kb][rg ^ (kb * 2)][0]);
      bu[n] = *reinterpret_cast<const short8*>(&lB[kb][(rg + 64) ^ (kb * 2)][0]);
    }
#pragma unroll
    for (int m = 0; m < 4; ++m)
#pragma unroll
      for (int n = 0; n < 2; ++n) {
        accg[m][n] = __builtin_amdgcn_mfma_f32_16x16x32_bf16(a[m], bg[n], accg[m][n], 0, 0, 0);
        accu[m][n] = __builtin_amdgcn_mfma_f32_16x16x32_bf16(a[m], bu[n], accu[m][n], 0, 0, 0);
      }
    __syncthreads();
  }
#pragma unroll
  for (int m = 0; m < 4; ++m)
#pragma unroll
    for (int n = 0; n < 2; ++n)
#pragma unroll
      for (int rr = 0; rr < 4; ++rr) {
        const int row = m0 + wr * 64 + m * 16 + kb * 4 + rr;
        const int col = n0 + wc * 32 + n * 16 + fr;
        const float g = accg[m][n][rr], u = accu[m][n][rr];
        Hout[(size_t)row * INTER + col] = f2bf(g / (1.0f + __expf(-g)) * u);
      }
}

__global__ __launch_bounds__(256, 2)
void gemm2_slow(const unsigned short* __restrict__ Hin, const float* __restrict__ W,
                float* __restrict__ Out) {
  __shared__ unsigned short lA[4][128][8];
  __shared__ unsigned short lB[4][128][8];
  const int t = threadIdx.x, lane = t & 63, wv = t >> 6;
  const int wr = wv >> 1, wc = wv & 1, fr = lane & 15, kb = lane >> 4;
  const int m0 = blockIdx.x * 128, n0 = blockIdx.y * 128;
  const int srow = t >> 3, scol = (t & 7) * 4, skb = (t & 7) >> 1, shalf = t & 1;
  f32x4 acc[4][4];
  const f32x4 z = {0.f, 0.f, 0.f, 0.f};
#pragma unroll
  for (int m = 0; m < 4; ++m)
#pragma unroll
    for (int n = 0; n < 4; ++n) acc[m][n] = z;
  for (int k0 = 0; k0 < INTER; k0 += 32) {
#pragma unroll
    for (int i = 0; i < 2; ++i) {
      const int row = (t >> 2) + 64 * i;
      const int kblk = t & 3;
      const uint4 v = *reinterpret_cast<const uint4*>(&Hin[(size_t)(m0 + row) * INTER + k0 + kblk * 8]);
      *reinterpret_cast<uint4*>(&lA[kblk][row ^ (kblk * 2)][0]) = v;
    }
#pragma unroll
    for (int i = 0; i < 4; ++i) {
      const int row = srow + 32 * i;
      const float4 v = *reinterpret_cast<const float4*>(&W[(size_t)(n0 + row) * INTER + k0 + scol]);
      ushort4v p; p.x = f2bf(v.x); p.y = f2bf(v.y); p.z = f2bf(v.z); p.w = f2bf(v.w);
      *reinterpret_cast<ushort4v*>(&lB[skb][row ^ (skb * 2)][shalf * 4]) = p;
    }
    __syncthreads();
    short8 a[4], b[4];
#pragma unroll
    for (int m = 0; m < 4; ++m) {
      const int rr = wr * 64 + m * 16 + fr;
      a[m] = *reinterpret_cast<const short8*>(&lA[kb][rr ^ (kb * 2)][0]);
    }
#pragma unroll
    for (int n = 0; n < 4; ++n) {
      const int rb = wc * 64 + n * 16 + fr;
      b[n] = *reinterpret_cast<const short8*>(&lB[kb][rb ^ (kb * 2)][0]);
    }
#pragma unroll
    for (int m = 0; m < 4; ++m)
#pragma unroll
      for (int n = 0; n < 4; ++n)
        acc[m][n] = __builtin_amdgcn_mfma_f32_16x16x32_bf16(a[m], b[n], acc[m][n], 0, 0, 0);
    __syncthreads();
  }
#pragma unroll
  for (int m = 0; m < 4; ++m)
#pragma unroll
    for (int n = 0; n < 4; ++n)
#pragma unroll
      for (int rr = 0; rr < 4; ++rr) {
        const int row = m0 + wr * 64 + m * 16 + kb * 4 + rr;
        const int col = n0 + wc * 64 + n * 16 + fr;
        Out[(size_t)row * HID + col] = acc[m][n][rr];
      }
}

// ---------------------------------------------------------------------------
extern "C" void kernel_launch(void* const* d_in, const int* in_sizes, int n_in,
                              void* d_out, int out_size, void* d_ws, size_t ws_size,
                              hipStream_t stream) {
  const float* x   = (const float*)d_in[0];
  const float* wgu = (const float*)d_in[1];
  const float* wdn = (const float*)d_in[2];
  float* out = (float*)d_out;

  const size_t szWgu = (size_t)2 * INTER * HID * 2;   // 180,355,072 B
  const size_t szWdn = (size_t)HID * INTER * 2;       //  90,177,536 B
  const size_t perRow = (size_t)(HID + INTER) * 2;    //  30,208 B (x_bf + h row)

  if (ws_size >= szWgu + szWdn + 128 * perRow) {
    // ---------- fast path: everything bf16 ----------
    unsigned short* wguB = (unsigned short*)d_ws;
    unsigned short* wdnB = wguB + (size_t)2 * INTER * HID;
    unsigned short* xB   = wdnB + (size_t)HID * INTER;

    size_t rows_fit = (ws_size - szWgu - szWdn) / perRow;
    int CM = (int)(rows_fit & ~(size_t)127);
    if (CM > MTOT) CM = MTOT;
    unsigned short* hB = xB + (size_t)CM * HID;

    cvt_kernel<<<2048, 256, 0, stream>>>(wgu, wguB, (long)2 * INTER * HID / 8);
    cvt_kernel<<<2048, 256, 0, stream>>>(wdn, wdnB, (long)HID * INTER / 8);

    for (int m0 = 0; m0 < MTOT; m0 += CM) {
      const int rows = (MTOT - m0 < CM) ? (MTOT - m0) : CM;
      const int mt = rows / 128;
      cvt_kernel<<<1024, 256, 0, stream>>>(x + (size_t)m0 * HID, xB,
                                           (long)rows * HID / 8);
      gemm1_fast<<<mt * (INTER / 64), 256, 0, stream>>>(xB, wguB, hB, mt);
      gemm2_fast<<<mt * (HID / 128), 256, 0, stream>>>(hB, wdnB,
                                                       out + (size_t)m0 * HID, mt);
    }
  } else {
    // ---------- fallback: baseline reg-cvt path ----------
    unsigned short* hbuf = (unsigned short*)d_ws;
    const size_t bpr = (size_t)INTER * 2;
    size_t rows_fit = ws_size / bpr;
    int chunk = (int)(rows_fit & ~(size_t)127);
    if (chunk <= 0) chunk = 128;
    if (chunk > MTOT) chunk = MTOT;
    for (int m0 = 0; m0 < MTOT; m0 += chunk) {
      const int mrows = (MTOT - m0 < chunk) ? (MTOT - m0) : chunk;
      dim3 g1(mrows / 128, INTER / 64);
      gemm1_slow<<<g1, dim3(256), 0, stream>>>(x + (size_t)m0 * HID, wgu, hbuf);
      dim3 g2(mrows / 128, HID / 128);
      gemm2_slow<<<g2, dim3(256), 0, stream>>>(hbuf, wdn, out + (size_t)m0 * HID);
    }
  }
}